// Round 1
// baseline (350.341 us; speedup 1.0000x reference)
//
#include <hip/hip_runtime.h>
#include <hip/hip_bf16.h>

// SRU cell, fp32 in / fp32 out (internal bf16 MFMA GEMM).
// u = x@W; then L-sequential scan parallel over B*d.
// L=1024, B=32, d=512. M=32768, K=512, N=1536.
// ws: Wt (bf16 [N][K], 1.5MB) | u (bf16 [M][N], 96MB)

typedef __attribute__((ext_vector_type(8))) __bf16 bf16x8;
typedef __attribute__((ext_vector_type(4))) __bf16 bf16x4;
typedef __attribute__((ext_vector_type(4))) float floatx4;

#define GK 512
#define GN 1536

// ---- convert + transpose weight: W[K][N] fp32 -> Wt[N][K] bf16 ---------------
__global__ __launch_bounds__(256) void cvt_w(const float* __restrict__ w,
                                             __bf16* __restrict__ wt) {
  int idx = blockIdx.x * 256 + threadIdx.x;  // 0..786431 = n*512+k
  int n = idx >> 9, k = idx & 511;
  wt[idx] = (__bf16)w[(size_t)k * GN + n];
}

// ---- GEMM: C[M][N] = A_f32[M][K] * Wt[N][K]^T, bf16 MFMA, bf16 out -----------
// 128x128 tile, BK=64 (8 K-iters). A: fp32 global -> reg cvt -> swizzled LDS
// (folds the x->bf16 conversion pass into the GEMM). B: async global_load_lds
// w/ per-lane swizzled source. XOR swizzle (chunk ^= row&7) keeps all
// ds_read_b128 at 2-way bank aliasing (free per m136).
__global__ __launch_bounds__(256, 2) void gemm_kernel(const float* __restrict__ A,
                                                      const __bf16* __restrict__ Bt,
                                                      __bf16* __restrict__ C) {
  __shared__ __attribute__((aligned(16))) __bf16 As[128 * 64];
  __shared__ __attribute__((aligned(16))) __bf16 Bs[128 * 64];
  const int m0 = blockIdx.y * 128;
  const int n0 = blockIdx.x * 128;
  const int t = threadIdx.x;
  const int wave = t >> 6, lane = t & 63;
  const int quad = lane >> 4, l16 = lane & 15;
  const int wm = (wave >> 1) * 64, wn = (wave & 1) * 64;

  floatx4 acc[4][4] = {};

  const int ar = t >> 4;         // row group index (0..15)
  const int ak = (t & 15) * 4;   // k element offset within BK
  const int ac = (t & 15) >> 1;  // 16B-chunk within row
  const int ah = t & 1;          // 8B half within chunk
  float4 areg[8];

  // prologue: A loads for k0 = 0 (coalesced: instr q covers rows q*16..q*16+15)
#pragma unroll
  for (int q = 0; q < 8; ++q)
    areg[q] = *(const float4*)(A + (size_t)(m0 + q * 16 + ar) * GK + ak);

  for (int kk = 0; kk < 8; ++kk) {
    const int k0 = kk * 64;
    // B async staging: wave covers rows wave*32..+32, 4 rounds of 8 rows
#pragma unroll
    for (int q = 0; q < 4; ++q) {
      int rb = wave * 4 + q;
      int n = rb * 8 + (lane >> 3);
      int c = lane & 7;
      const __bf16* src = Bt + (size_t)(n0 + n) * GK + k0 + ((c ^ (n & 7)) * 8);
      __builtin_amdgcn_global_load_lds(
          (const __attribute__((address_space(1))) void*)src,
          (__attribute__((address_space(3))) void*)(Bs + rb * 512), 16, 0, 0);
    }
    // A: convert prefetched regs -> swizzled LDS
#pragma unroll
    for (int q = 0; q < 8; ++q) {
      int r = q * 16 + ar;
      float4 v = areg[q];
      bf16x4 o = {(__bf16)v.x, (__bf16)v.y, (__bf16)v.z, (__bf16)v.w};
      *(bf16x4*)(As + r * 64 + (ac ^ (r & 7)) * 8 + ah * 4) = o;
    }
    __syncthreads();
    // software-prefetch A for next iter (drains at end-of-iter barrier)
    if (kk < 7) {
#pragma unroll
      for (int q = 0; q < 8; ++q)
        areg[q] = *(const float4*)(A + (size_t)(m0 + q * 16 + ar) * GK + k0 + 64 + ak);
    }
    // compute: 2 k-windows of 32
#pragma unroll
    for (int ks = 0; ks < 2; ++ks) {
      bf16x8 af[4], bfr[4];
#pragma unroll
      for (int tt = 0; tt < 4; ++tt) {
        int m = wm + tt * 16 + l16;
        af[tt] = *(const bf16x8*)(As + m * 64 + (((ks * 4 + quad) ^ (m & 7)) * 8));
        int n = wn + tt * 16 + l16;
        bfr[tt] = *(const bf16x8*)(Bs + n * 64 + (((ks * 4 + quad) ^ (n & 7)) * 8));
      }
#pragma unroll
      for (int tm = 0; tm < 4; ++tm)
#pragma unroll
        for (int tn = 0; tn < 4; ++tn)
          acc[tm][tn] = __builtin_amdgcn_mfma_f32_16x16x32_bf16(
              af[tm], bfr[tn], acc[tm][tn], 0, 0, 0);
    }
    __syncthreads();
  }

  // epilogue: C/D layout col=lane&15, row=quad*4+reg (m89-verified)
#pragma unroll
  for (int tm = 0; tm < 4; ++tm)
#pragma unroll
    for (int tn = 0; tn < 4; ++tn)
#pragma unroll
      for (int i = 0; i < 4; ++i) {
        int m = m0 + wm + tm * 16 + quad * 4 + i;
        int n = n0 + wn + tn * 16 + l16;
        C[(size_t)m * GN + n] = (__bf16)acc[tm][tn][i];
      }
}

// ---- SRU scan: barrier-free, 1 wave/block, register ping-pong prefetch ------
// 256 blocks x 64 threads. Block g owns 64 channels: b=g>>3, j=j0+lane.
// Per-lane direct global loads are already coalesced (64 consecutive channels
// -> 128B ushort / 256B dword segments per wave). 2x32-step register
// double-buffer: issue batch tb+32's 128 loads, compute batch tb from regs.
// ~20KB in flight per CU hides HBM latency; no LDS, no __syncthreads, no
// vmcnt(0) drains (old producer/consumer paid a full drain per 16-step stage).
#define SD 32  // prefetch depth (steps per half-batch); 1024 % (2*SD) == 0
__global__ __launch_bounds__(64, 1) void scan_kernel(
    const __bf16* __restrict__ u, const float* __restrict__ x,
    const float* __restrict__ wc, const float* __restrict__ bias,
    const float* __restrict__ c0, float* __restrict__ out) {
  const int g = blockIdx.x;
  const int b = g >> 3;
  const int j0 = (g & 7) * 64;
  const int lane = threadIdx.x;
  const int ob = b * 512 + j0 + lane;  // this lane's channel

  const float vf = wc[j0 + lane], vr = wc[512 + j0 + lane];
  const float bfv = bias[j0 + lane], brv = bias[512 + j0 + lane];
  float c = c0[ob];

  // per-step strides: u +49152 elems (t), +512 (component q); x/out +16384
  const __bf16* ub = u + (size_t)b * 1536 + j0 + lane;
  const float* xb = x + ob;
  float* op = out + ob;

  unsigned au0[SD], au1[SD], au2[SD];
  float ax[SD];
  unsigned bu0[SD], bu1[SD], bu2[SD];
  float bx[SD];

  // prologue: batch 0 -> A buffers
#pragma unroll
  for (int i = 0; i < SD; ++i) {
    const __bf16* p = ub + (size_t)i * 49152;
    au0[i] = *(const unsigned short*)(p);
    au1[i] = *(const unsigned short*)(p + 512);
    au2[i] = *(const unsigned short*)(p + 1024);
    ax[i] = xb[(size_t)i * 16384];
  }

  // One half: issue loads for (TB+SD) into N*, compute steps TB..TB+SD-1 from
  // C*. All array indices compile-time (full unroll) so buffers stay in VGPRs.
#define SCAN_HALF(C0, C1, C2, CX, N0, N1, N2, NX, TB)                       \
  {                                                                         \
    if ((TB) + SD < 1024) {                                                 \
      const __bf16* p0 = ub + (size_t)((TB) + SD) * 49152;                  \
      const float* px = xb + (size_t)((TB) + SD) * 16384;                   \
      _Pragma("unroll") for (int i = 0; i < SD; ++i) {                      \
        const __bf16* p = p0 + (size_t)i * 49152;                           \
        N0[i] = *(const unsigned short*)(p);                                \
        N1[i] = *(const unsigned short*)(p + 512);                          \
        N2[i] = *(const unsigned short*)(p + 1024);                         \
        NX[i] = px[(size_t)i * 16384];                                      \
      }                                                                     \
    }                                                                       \
    _Pragma("unroll") for (int i = 0; i < SD; ++i) {                        \
      float u0 = __uint_as_float(C0[i] << 16);                              \
      float u1 = __uint_as_float(C1[i] << 16);                              \
      float u2 = __uint_as_float(C2[i] << 16);                              \
      float a1 = __builtin_fmaf(vf, c, u1 + bfv);                           \
      float f = __builtin_amdgcn_rcpf(1.f + __expf(-a1));                   \
      c = __builtin_fmaf(f, c - u0, u0);                                    \
      float a2 = __builtin_fmaf(vr, c, u2 + brv);                           \
      float r = __builtin_amdgcn_rcpf(1.f + __expf(-a2));                   \
      float tt = __expf(-2.f * __builtin_fabsf(c));                         \
      float gg = (1.f - tt) * __builtin_amdgcn_rcpf(1.f + tt);              \
      gg = __builtin_copysignf(gg, c);                                      \
      float xs = CX[i] * 1.7320508075688772f;                               \
      float h = __builtin_fmaf(r, gg - xs, xs);                             \
      op[(size_t)((TB) + i) * 16384] = h;                                   \
    }                                                                       \
  }

  for (int tb = 0; tb < 1024; tb += 2 * SD) {
    SCAN_HALF(au0, au1, au2, ax, bu0, bu1, bu2, bx, tb);
    SCAN_HALF(bu0, bu1, bu2, bx, au0, au1, au2, ax, tb + SD);
  }
#undef SCAN_HALF

  out[(size_t)16777216 + ob] = c;  // c_last
}

extern "C" void kernel_launch(void* const* d_in, const int* in_sizes, int n_in,
                              void* d_out, int out_size, void* d_ws, size_t ws_size,
                              hipStream_t stream) {
  const float* x = (const float*)d_in[0];     // (1024,32,512) fp32
  const float* w = (const float*)d_in[1];     // (512,1536)    fp32
  const float* wc = (const float*)d_in[2];    // (1024,)       fp32
  const float* bias = (const float*)d_in[3];  // (1024,)       fp32
  const float* c0 = (const float*)d_in[4];    // (32,512)      fp32
  float* out = (float*)d_out;                 // h (L,B,d) | c_last (B,d)

  char* ws = (char*)d_ws;
  __bf16* wt = (__bf16*)ws;             // 1,572,864 B
  __bf16* u = (__bf16*)(ws + 1572864);  // 100,663,296 B

  cvt_w<<<3072, 256, 0, stream>>>(w, wt);
  dim3 gg(12, 256);
  gemm_kernel<<<gg, 256, 0, stream>>>(x, wt, u);
  scan_kernel<<<256, 64, 0, stream>>>(u, x, wc, bias, c0, out);
}

// Round 2
// 291.080 us; speedup vs baseline: 1.2036x; 1.2036x over previous
//
#include <hip/hip_runtime.h>
#include <hip/hip_bf16.h>

// SRU cell, fp32 in / fp32 out (internal bf16 MFMA GEMM).
// u = x@W; then L-sequential scan parallel over B*d.
// L=1024, B=32, d=512. M=32768, K=512, N=1536.
// ws: Wt (bf16 [N][K], 1.5MB) | u (bf16 [M][N], 96MB)

typedef __attribute__((ext_vector_type(8))) __bf16 bf16x8;
typedef __attribute__((ext_vector_type(4))) __bf16 bf16x4;
typedef __attribute__((ext_vector_type(4))) float floatx4;

#define GK 512
#define GN 1536

#define WAITV(N) asm volatile("s_waitcnt vmcnt(" #N ")" ::: "memory")
#define WAITVL0() asm volatile("s_waitcnt vmcnt(0) lgkmcnt(0)" ::: "memory")
#define FENCE() asm volatile("" ::: "memory")

// ---- convert + transpose weight: W[K][N] fp32 -> Wt[N][K] bf16 ---------------
__global__ __launch_bounds__(256) void cvt_w(const float* __restrict__ w,
                                             __bf16* __restrict__ wt) {
  int idx = blockIdx.x * 256 + threadIdx.x;  // 0..786431 = n*512+k
  int n = idx >> 9, k = idx & 511;
  wt[idx] = (__bf16)w[(size_t)k * GN + n];
}

// ---- GEMM: C[M][N] = A_f32[M][K] * Wt[N][K]^T, bf16 MFMA, bf16 out -----------
// 128x128 tile, BK=64, T3 2-phase pipeline: double-buffered LDS, stage tile
// t+1 while computing tile t, ONE raw s_barrier per iter with counted vmcnt
// (A regs ready at vmcnt(4); full vmcnt(0) only after the MFMA phase so B's
// global_load_lds lands under compute). XOR swizzle (chunk ^= row&7) keeps
// ds_read_b128 at free 2-way aliasing. Bijective XCD swizzle: each XCD owns
// 32 contiguous m-rows x all 12 n-panels (A panel + Wt fit its 4MB L2).
__global__ __launch_bounds__(256, 2) void gemm_kernel(const float* __restrict__ A,
                                                      const __bf16* __restrict__ Bt,
                                                      __bf16* __restrict__ C) {
  __shared__ __attribute__((aligned(16))) __bf16 As[2][128 * 64];
  __shared__ __attribute__((aligned(16))) __bf16 Bs[2][128 * 64];
  // XCD-aware remap: dispatch id -> contiguous work chunk per XCD (3072%8==0)
  const int id = blockIdx.y * 12 + blockIdx.x;
  const int wk = (id & 7) * 384 + (id >> 3);
  const int n0 = (wk % 12) * 128;
  const int m0 = (wk / 12) * 128;
  const int t = threadIdx.x;
  const int wave = t >> 6, lane = t & 63;
  const int quad = lane >> 4, l16 = lane & 15;
  const int wm = (wave >> 1) * 64, wn = (wave & 1) * 64;

  floatx4 acc[4][4] = {};

  const int ar = t >> 4;         // row group index (0..15)
  const int ak = (t & 15) * 4;   // k element offset within BK
  const int ac = (t & 15) >> 1;  // 16B-chunk within row
  const int ah = t & 1;          // 8B half within chunk
  float4 areg[8];

  // ---- prologue: stage tile 0 into buffer 0 ----
#pragma unroll
  for (int q = 0; q < 8; ++q)  // A first (8 loads)...
    areg[q] = *(const float4*)(A + (size_t)(m0 + q * 16 + ar) * GK + ak);
#pragma unroll
  for (int q = 0; q < 4; ++q) {  // ...then B (4 loads) so vmcnt(4) => A done
    int rb = wave * 4 + q;
    int n = rb * 8 + (lane >> 3);
    int cB = lane & 7;
    const __bf16* src = Bt + (size_t)(n0 + n) * GK + ((cB ^ (n & 7)) * 8);
    __builtin_amdgcn_global_load_lds(
        (const __attribute__((address_space(1))) void*)src,
        (__attribute__((address_space(3))) void*)(&Bs[0][0] + rb * 512), 16, 0, 0);
  }
  WAITV(4);  // A regs landed; B may still be in flight
#pragma unroll
  for (int q = 0; q < 8; ++q) {
    int r = q * 16 + ar;
    float4 v = areg[q];
    bf16x4 o = {(__bf16)v.x, (__bf16)v.y, (__bf16)v.z, (__bf16)v.w};
    *(bf16x4*)(&As[0][0] + r * 64 + (ac ^ (r & 7)) * 8 + ah * 4) = o;
  }
  WAITVL0();
  __builtin_amdgcn_s_barrier();
  FENCE();

  // ---- main loop: compute tile tt from buf c, stage tile tt+1 into buf c^1 --
  for (int tt = 0; tt < 8; ++tt) {
    const int c = tt & 1;
    const __bf16* Acur = &As[c][0];
    const __bf16* Bcur = &Bs[c][0];
    if (tt < 7) {
      const int k1 = (tt + 1) * 64;
      // issue next-tile loads BEFORE the MFMA phase (A first, then B)
#pragma unroll
      for (int q = 0; q < 8; ++q)
        areg[q] = *(const float4*)(A + (size_t)(m0 + q * 16 + ar) * GK + k1 + ak);
#pragma unroll
      for (int q = 0; q < 4; ++q) {
        int rb = wave * 4 + q;
        int n = rb * 8 + (lane >> 3);
        int cB = lane & 7;
        const __bf16* src = Bt + (size_t)(n0 + n) * GK + k1 + ((cB ^ (n & 7)) * 8);
        __builtin_amdgcn_global_load_lds(
            (const __attribute__((address_space(1))) void*)src,
            (__attribute__((address_space(3))) void*)(&Bs[c ^ 1][0] + rb * 512),
            16, 0, 0);
      }
    }
    // compute: 2 k-windows of 32
#pragma unroll
    for (int ks = 0; ks < 2; ++ks) {
      bf16x8 af[4], bfr[4];
#pragma unroll
      for (int q = 0; q < 4; ++q) {
        int m = wm + q * 16 + l16;
        af[q] = *(const bf16x8*)(Acur + m * 64 + (((ks * 4 + quad) ^ (m & 7)) * 8));
        int n = wn + q * 16 + l16;
        bfr[q] = *(const bf16x8*)(Bcur + n * 64 + (((ks * 4 + quad) ^ (n & 7)) * 8));
      }
#pragma unroll
      for (int tm = 0; tm < 4; ++tm)
#pragma unroll
        for (int tn = 0; tn < 4; ++tn)
          acc[tm][tn] = __builtin_amdgcn_mfma_f32_16x16x32_bf16(
              af[tm], bfr[tn], acc[tm][tn], 0, 0, 0);
    }
    if (tt < 7) {
      WAITV(4);  // A(t+1) regs landed (B's 4 gload_lds may remain)
#pragma unroll
      for (int q = 0; q < 8; ++q) {
        int r = q * 16 + ar;
        float4 v = areg[q];
        bf16x4 o = {(__bf16)v.x, (__bf16)v.y, (__bf16)v.z, (__bf16)v.w};
        *(bf16x4*)(&As[c ^ 1][0] + r * 64 + (ac ^ (r & 7)) * 8 + ah * 4) = o;
      }
      WAITVL0();  // B(t+1) landed in LDS, my ds ops done
      __builtin_amdgcn_s_barrier();
      FENCE();
    }
  }

  // epilogue: C/D layout col=lane&15, row=quad*4+reg (m89-verified)
#pragma unroll
  for (int tm = 0; tm < 4; ++tm)
#pragma unroll
    for (int tn = 0; tn < 4; ++tn)
#pragma unroll
      for (int i = 0; i < 4; ++i) {
        int m = m0 + wm + tm * 16 + quad * 4 + i;
        int n = n0 + wn + tn * 16 + l16;
        C[(size_t)m * GN + n] = (__bf16)acc[tm][tn][i];
      }
}

// ---- SRU scan: producer/consumer, 4-deep ring, counted vmcnt, raw barriers --
// 256 blocks x 128 thr. Block g owns 64 channels: b=g>>3, j=j0+lane.
// Producer (wave1) keeps 3 stages (30 loads, ~30KB) in flight; per stage it
// waits vmcnt(20) (= oldest stage landed), barriers, issues stage s+3 (slot
// (s-1)&3, which the consumer finished before this barrier). Consumer (wave0)
// never waits on anything but the barrier -- its own vmcnt only tracks its
// fire-and-forget h stores. No __syncthreads => no full drain anywhere.
__global__ __launch_bounds__(128, 1) void scan_kernel(
    const __bf16* __restrict__ u, const float* __restrict__ x,
    const float* __restrict__ wc, const float* __restrict__ bias,
    const float* __restrict__ c0, float* __restrict__ out) {
  __shared__ __attribute__((aligned(16))) unsigned char ring[4][10240];
  const int g = blockIdx.x;
  const int b = g >> 3;
  const int j0 = (g & 7) * 64;
  const int wave = threadIdx.x >> 6;
  const int lane = threadIdx.x & 63;
  const int ob = b * 512 + j0 + lane;  // this lane's channel (consumer)

  if (wave == 1) {
    // producer: per-lane time-invariant element offsets
    int pre_u[6], pre_x[4];
#pragma unroll
    for (int r = 0; r < 6; ++r) {
      int seg = r * 8 + (lane >> 3);  // seg = i*3 + q
      int i = seg / 3;
      int q = seg - i * 3;
      pre_u[r] = i * 49152 + b * 1536 + q * 512 + j0 + (lane & 7) * 8;
    }
#pragma unroll
    for (int r = 0; r < 4; ++r) {
      int i = r * 4 + (lane >> 4);
      pre_x[r] = i * 16384 + b * 512 + j0 + (lane & 15) * 4;
    }
#define ISSUE(st)                                                              \
  {                                                                            \
    unsigned char* base = ring[(st) & 3];                                      \
    size_t tu = (size_t)(st) * 16 * 49152;                                     \
    size_t tx = (size_t)(st) * 16 * 16384;                                     \
    _Pragma("unroll") for (int r = 0; r < 6; ++r)                              \
        __builtin_amdgcn_global_load_lds(                                      \
            (const __attribute__((address_space(1))) void*)(u + tu + pre_u[r]),\
            (__attribute__((address_space(3))) void*)(base + r * 1024), 16, 0, \
            0);                                                                \
    _Pragma("unroll") for (int r = 0; r < 4; ++r)                              \
        __builtin_amdgcn_global_load_lds(                                      \
            (const __attribute__((address_space(1))) void*)(x + tx + pre_x[r]),\
            (__attribute__((address_space(3))) void*)(base + 6144 + r * 1024), \
            16, 0, 0);                                                         \
  }
    ISSUE(0);
    ISSUE(1);
    ISSUE(2);
    for (int s = 0; s < 64; ++s) {
      if (s < 62) {
        WAITV(20);  // stage s's 10 loads (oldest) have landed
      } else if (s == 62) {
        WAITV(10);
      } else {
        WAITV(0);
      }
      __builtin_amdgcn_s_barrier();  // release stage s to consumer
      FENCE();
      if (s + 3 < 64) ISSUE(s + 3);  // slot (s-1)&3: consumer done with it
    }
#undef ISSUE
  } else {
    // consumer
    const float vf = wc[j0 + lane], vr = wc[512 + j0 + lane];
    const float bfv = bias[j0 + lane], brv = bias[512 + j0 + lane];
    float c = c0[ob];
    float* op = out + ob;
    for (int s = 0; s < 64; ++s) {
      __builtin_amdgcn_s_barrier();  // stage s now valid
      FENCE();
      const unsigned char* base = ring[s & 3];
#pragma unroll
      for (int i = 0; i < 16; ++i) {
        float u0 = (float)*(const __bf16*)(base + i * 384 + lane * 2);
        float u1 = (float)*(const __bf16*)(base + i * 384 + 128 + lane * 2);
        float u2 = (float)*(const __bf16*)(base + i * 384 + 256 + lane * 2);
        float xv = *(const float*)(base + 6144 + i * 256 + lane * 4);
        float a1 = __builtin_fmaf(vf, c, u1 + bfv);
        float f = __builtin_amdgcn_rcpf(1.f + __expf(-a1));
        c = __builtin_fmaf(f, c - u0, u0);
        float a2 = __builtin_fmaf(vr, c, u2 + brv);
        float r = __builtin_amdgcn_rcpf(1.f + __expf(-a2));
        float tt = __expf(-2.f * __builtin_fabsf(c));
        float gg = (1.f - tt) * __builtin_amdgcn_rcpf(1.f + tt);
        gg = __builtin_copysignf(gg, c);
        float xs = xv * 1.7320508075688772f;
        float h = __builtin_fmaf(r, gg - xs, xs);
        op[(size_t)(s * 16 + i) * 16384] = h;
      }
      FENCE();  // keep this stage's LDS reads inside the stage window
    }
    out[(size_t)16777216 + ob] = c;  // c_last
  }
}

extern "C" void kernel_launch(void* const* d_in, const int* in_sizes, int n_in,
                              void* d_out, int out_size, void* d_ws, size_t ws_size,
                              hipStream_t stream) {
  const float* x = (const float*)d_in[0];     // (1024,32,512) fp32
  const float* w = (const float*)d_in[1];     // (512,1536)    fp32
  const float* wc = (const float*)d_in[2];    // (1024,)       fp32
  const float* bias = (const float*)d_in[3];  // (1024,)       fp32
  const float* c0 = (const float*)d_in[4];    // (32,512)      fp32
  float* out = (float*)d_out;                 // h (L,B,d) | c_last (B,d)

  char* ws = (char*)d_ws;
  __bf16* wt = (__bf16*)ws;             // 1,572,864 B
  __bf16* u = (__bf16*)(ws + 1572864);  // 100,663,296 B

  cvt_w<<<3072, 256, 0, stream>>>(w, wt);
  dim3 gg(12, 256);
  gemm_kernel<<<gg, 256, 0, stream>>>(x, wt, u);
  scan_kernel<<<256, 128, 0, stream>>>(u, x, wc, bias, c0, out);
}

// Round 3
// 280.292 us; speedup vs baseline: 1.2499x; 1.0385x over previous
//
#include <hip/hip_runtime.h>
#include <hip/hip_bf16.h>

// SRU cell, fp32 in / fp32 out (internal bf16 MFMA GEMM).
// u = x@W; then L-sequential scan parallel over B*d.
// L=1024, B=32, d=512. M=32768, K=512, N=1536.
// ws: Wt (bf16 [N][K], 1.5MB) | u (bf16 [M][N], 96MB)

typedef __attribute__((ext_vector_type(8))) __bf16 bf16x8;
typedef __attribute__((ext_vector_type(4))) __bf16 bf16x4;
typedef __attribute__((ext_vector_type(4))) float floatx4;

#define GK 512
#define GN 1536

#define WAITV(N) asm volatile("s_waitcnt vmcnt(" #N ")" ::: "memory")
#define FENCE() asm volatile("" ::: "memory")

// ---- weight transpose: W[K][N] fp32 -> Wt[N][K] bf16, LDS-tiled -------------
// 64x64 tiles, coalesced global read AND write; +1-padded LDS kills conflicts.
__global__ __launch_bounds__(256) void cvt_w(const float* __restrict__ w,
                                             __bf16* __restrict__ wt) {
  __shared__ float tile[64][65];
  const int bk = blockIdx.x;  // 8 tiles along K
  const int bn = blockIdx.y;  // 24 tiles along N
  const int t = threadIdx.x;
  const int tr = t >> 6;   // 0..3
  const int tc = t & 63;   // 0..63
#pragma unroll
  for (int i = 0; i < 16; ++i) {
    int kl = i * 4 + tr;
    tile[kl][tc] = w[(size_t)(bk * 64 + kl) * GN + bn * 64 + tc];
  }
  __syncthreads();
#pragma unroll
  for (int i = 0; i < 16; ++i) {
    int nl = i * 4 + tr;
    wt[(size_t)(bn * 64 + nl) * GK + bk * 64 + tc] = (__bf16)tile[tc][nl];
  }
}

// ---- GEMM: C[M][N] = A_f32[M][K] * Wt[N][K]^T, bf16 MFMA, bf16 out -----------
// 128x128 tile, BK=64, depth-3 pipeline: 3 A-reg banks (AL(t+3) issued at
// iter t -> 2-iter HBM latency tolerance), 3-deep B LDS ring (BL(t+2); B is
// L2-hit after XCD swizzle so 1-iter suffices), ONE raw s_barrier per iter,
// all vmcnt waits counted (24/20 steady state, never 0 mid-loop). Fully
// hand-unrolled so every bank/buffer index is compile-time (VGPR-resident).
// XOR swizzle (chunk ^= row&7) keeps ds_read_b128 at free 2-way aliasing.
__global__ __launch_bounds__(256, 2) void gemm_kernel(const float* __restrict__ A,
                                                      const __bf16* __restrict__ Bt,
                                                      __bf16* __restrict__ C) {
  __shared__ __attribute__((aligned(16))) __bf16 As[2][128 * 64];
  __shared__ __attribute__((aligned(16))) __bf16 Bs[3][128 * 64];
  // XCD-aware remap: each XCD owns 32 contiguous m-rows x all 12 n-panels
  const int id = blockIdx.y * 12 + blockIdx.x;
  const int wk = (id & 7) * 384 + (id >> 3);
  const int n0 = (wk % 12) * 128;
  const int m0 = (wk / 12) * 128;
  const int t = threadIdx.x;
  const int wave = t >> 6, lane = t & 63;
  const int quad = lane >> 4, l16 = lane & 15;
  const int wm = (wave >> 1) * 64, wn = (wave & 1) * 64;

  floatx4 acc[4][4] = {};

  const int ar = t >> 4;         // row group index (0..15)
  const int ak = (t & 15) * 4;   // k element offset within BK
  const int ac = (t & 15) >> 1;  // 16B-chunk within row
  const int ah = t & 1;          // 8B half within chunk
  float4 areg0[8], areg1[8], areg2[8];

#define ISSUE_A(BANK, KT)                                                    \
  _Pragma("unroll") for (int q = 0; q < 8; ++q) areg##BANK[q] =              \
      *(const float4*)(A + (size_t)(m0 + q * 16 + ar) * GK + (KT) * 64 + ak);

#define ISSUE_B(BUF, KT)                                                     \
  _Pragma("unroll") for (int q = 0; q < 4; ++q) {                            \
    int rb = wave * 4 + q;                                                   \
    int n = rb * 8 + (lane >> 3);                                            \
    int cB = lane & 7;                                                       \
    const __bf16* src =                                                      \
        Bt + (size_t)(n0 + n) * GK + (KT) * 64 + ((cB ^ (n & 7)) * 8);       \
    __builtin_amdgcn_global_load_lds(                                        \
        (const __attribute__((address_space(1))) void*)src,                  \
        (__attribute__((address_space(3))) void*)(&Bs[BUF][0] + rb * 512),   \
        16, 0, 0);                                                           \
  }

#define CVT_A(BANK, ABUF)                                                    \
  _Pragma("unroll") for (int q = 0; q < 8; ++q) {                            \
    int r = q * 16 + ar;                                                     \
    float4 v = areg##BANK[q];                                                \
    bf16x4 o = {(__bf16)v.x, (__bf16)v.y, (__bf16)v.z, (__bf16)v.w};         \
    *(bf16x4*)(&As[ABUF][0] + r * 64 + (ac ^ (r & 7)) * 8 + ah * 4) = o;     \
  }

#define COMPUTE(ABUF, BBUF)                                                  \
  _Pragma("unroll") for (int ks = 0; ks < 2; ++ks) {                         \
    bf16x8 af[4], bfr[4];                                                    \
    _Pragma("unroll") for (int q = 0; q < 4; ++q) {                          \
      int m = wm + q * 16 + l16;                                             \
      af[q] = *(const bf16x8*)(&As[ABUF][0] + m * 64 +                       \
                               (((ks * 4 + quad) ^ (m & 7)) * 8));           \
      int n = wn + q * 16 + l16;                                             \
      bfr[q] = *(const bf16x8*)(&Bs[BBUF][0] + n * 64 +                      \
                                (((ks * 4 + quad) ^ (n & 7)) * 8));          \
    }                                                                        \
    _Pragma("unroll") for (int tm = 0; tm < 4; ++tm)                         \
        _Pragma("unroll") for (int tn = 0; tn < 4; ++tn) acc[tm][tn] =       \
            __builtin_amdgcn_mfma_f32_16x16x32_bf16(af[tm], bfr[tn],         \
                                                    acc[tm][tn], 0, 0, 0);   \
  }

#define BAR()                                              \
  do {                                                     \
    asm volatile("s_waitcnt lgkmcnt(0)" ::: "memory");     \
    __builtin_amdgcn_s_barrier();                          \
    FENCE();                                               \
  } while (0)

  // bank[t%3] holds AL(t); As[t&1] holds tile t; Bs[t%3] holds BL(t).
  // prologue: AL0,BL0,AL1,BL1,AL2 in flight (32 ops)
  ISSUE_A(0, 0);
  ISSUE_B(0, 0);
  ISSUE_A(1, 1);
  ISSUE_B(1, 1);
  ISSUE_A(2, 2);
  WAITV(24);  // AL0 landed
  CVT_A(0, 0);
  WAITV(20);  // BL0 landed
  BAR();
  // iter 0: compute tile0; stage BL2, AL3; convert A1
  ISSUE_B(2, 2);
  ISSUE_A(0, 3);
  WAITV(24);  // AL1 landed
  CVT_A(1, 1);
  COMPUTE(0, 0);
  WAITV(20);  // BL1 landed
  BAR();
  // iter 1
  ISSUE_B(0, 3);
  ISSUE_A(1, 4);
  WAITV(24);  // AL2
  CVT_A(2, 0);
  COMPUTE(1, 1);
  WAITV(20);  // BL2
  BAR();
  // iter 2
  ISSUE_B(1, 4);
  ISSUE_A(2, 5);
  WAITV(24);  // AL3
  CVT_A(0, 1);
  COMPUTE(0, 2);
  WAITV(20);  // BL3
  BAR();
  // iter 3
  ISSUE_B(2, 5);
  ISSUE_A(0, 6);
  WAITV(24);  // AL4
  CVT_A(1, 0);
  COMPUTE(1, 0);
  WAITV(20);  // BL4
  BAR();
  // iter 4
  ISSUE_B(0, 6);
  ISSUE_A(1, 7);
  WAITV(24);  // AL5
  CVT_A(2, 1);
  COMPUTE(0, 1);
  WAITV(20);  // BL5
  BAR();
  // iter 5 (no AL8)
  ISSUE_B(1, 7);
  WAITV(16);  // AL6
  CVT_A(0, 0);
  COMPUTE(1, 2);
  WAITV(12);  // BL6
  BAR();
  // iter 6 (no issues)
  WAITV(4);  // AL7
  CVT_A(1, 1);
  COMPUTE(0, 0);
  WAITV(0);  // BL7
  BAR();
  // iter 7
  COMPUTE(1, 1);

#undef ISSUE_A
#undef ISSUE_B
#undef CVT_A
#undef COMPUTE
#undef BAR

  // epilogue: C/D layout col=lane&15, row=quad*4+reg (m89-verified)
#pragma unroll
  for (int tm = 0; tm < 4; ++tm)
#pragma unroll
    for (int tn = 0; tn < 4; ++tn)
#pragma unroll
      for (int i = 0; i < 4; ++i) {
        int m = m0 + wm + tm * 16 + quad * 4 + i;
        int n = n0 + wn + tn * 16 + l16;
        C[(size_t)m * GN + n] = (__bf16)acc[tm][tn][i];
      }
}

// ---- SRU scan: producer/consumer, 8-deep ring, counted vmcnt, raw barriers --
// 256 blocks x 128 thr. Block g owns 64 channels: b=g>>3, j=j0+lane.
// Producer (wave1) keeps 7 stages (70 loads, ~70KB) in flight: with 256
// blocks there is ~8MB in flight chip-wide => effective load latency ~1.2us
// (queueing); 7-stage lookahead (~2.5us) covers it where 3-deep was marginal.
// Consumer (wave0) waits only on barriers; its vmcnt tracks only its own
// fire-and-forget h stores. No __syncthreads => no full drain anywhere.
__global__ __launch_bounds__(128, 1) void scan_kernel(
    const __bf16* __restrict__ u, const float* __restrict__ x,
    const float* __restrict__ wc, const float* __restrict__ bias,
    const float* __restrict__ c0, float* __restrict__ out) {
  __shared__ __attribute__((aligned(16))) unsigned char ring[8][10240];
  const int g = blockIdx.x;
  const int b = g >> 3;
  const int j0 = (g & 7) * 64;
  const int wave = threadIdx.x >> 6;
  const int lane = threadIdx.x & 63;
  const int ob = b * 512 + j0 + lane;  // this lane's channel (consumer)

  if (wave == 1) {
    // producer: per-lane time-invariant element offsets
    int pre_u[6], pre_x[4];
#pragma unroll
    for (int r = 0; r < 6; ++r) {
      int seg = r * 8 + (lane >> 3);  // seg = i*3 + q
      int i = seg / 3;
      int q = seg - i * 3;
      pre_u[r] = i * 49152 + b * 1536 + q * 512 + j0 + (lane & 7) * 8;
    }
#pragma unroll
    for (int r = 0; r < 4; ++r) {
      int i = r * 4 + (lane >> 4);
      pre_x[r] = i * 16384 + b * 512 + j0 + (lane & 15) * 4;
    }
#define ISSUE(st)                                                              \
  {                                                                            \
    unsigned char* base = ring[(st) & 7];                                      \
    size_t tu = (size_t)(st) * 16 * 49152;                                     \
    size_t tx = (size_t)(st) * 16 * 16384;                                     \
    _Pragma("unroll") for (int r = 0; r < 6; ++r)                              \
        __builtin_amdgcn_global_load_lds(                                      \
            (const __attribute__((address_space(1))) void*)(u + tu + pre_u[r]),\
            (__attribute__((address_space(3))) void*)(base + r * 1024), 16, 0, \
            0);                                                                \
    _Pragma("unroll") for (int r = 0; r < 4; ++r)                              \
        __builtin_amdgcn_global_load_lds(                                      \
            (const __attribute__((address_space(1))) void*)(x + tx + pre_x[r]),\
            (__attribute__((address_space(3))) void*)(base + 6144 + r * 1024), \
            16, 0, 0);                                                         \
  }
    ISSUE(0);
    ISSUE(1);
    ISSUE(2);
    ISSUE(3);
    ISSUE(4);
    ISSUE(5);
    ISSUE(6);
    for (int s = 0; s < 64; ++s) {
      // wait until stage s (oldest outstanding) has landed
      if (s < 58) {
        WAITV(60);
      } else if (s == 58) {
        WAITV(50);
      } else if (s == 59) {
        WAITV(40);
      } else if (s == 60) {
        WAITV(30);
      } else if (s == 61) {
        WAITV(20);
      } else if (s == 62) {
        WAITV(10);
      } else {
        WAITV(0);
      }
      __builtin_amdgcn_s_barrier();  // release stage s to consumer
      FENCE();
      if (s + 7 < 64) ISSUE(s + 7);  // slot (s-1)&7: consumer done with it
    }
#undef ISSUE
  } else {
    // consumer
    const float vf = wc[j0 + lane], vr = wc[512 + j0 + lane];
    const float bfv = bias[j0 + lane], brv = bias[512 + j0 + lane];
    float c = c0[ob];
    float* op = out + ob;
    for (int s = 0; s < 64; ++s) {
      __builtin_amdgcn_s_barrier();  // stage s now valid
      FENCE();
      const unsigned char* base = ring[s & 7];
#pragma unroll
      for (int i = 0; i < 16; ++i) {
        float u0 = (float)*(const __bf16*)(base + i * 384 + lane * 2);
        float u1 = (float)*(const __bf16*)(base + i * 384 + 128 + lane * 2);
        float u2 = (float)*(const __bf16*)(base + i * 384 + 256 + lane * 2);
        float xv = *(const float*)(base + 6144 + i * 256 + lane * 4);
        float a1 = __builtin_fmaf(vf, c, u1 + bfv);
        float f = __builtin_amdgcn_rcpf(1.f + __expf(-a1));
        c = __builtin_fmaf(f, c - u0, u0);
        float a2 = __builtin_fmaf(vr, c, u2 + brv);
        float r = __builtin_amdgcn_rcpf(1.f + __expf(-a2));
        float tt = __expf(-2.f * __builtin_fabsf(c));
        float gg = (1.f - tt) * __builtin_amdgcn_rcpf(1.f + tt);
        gg = __builtin_copysignf(gg, c);
        float xs = xv * 1.7320508075688772f;
        float h = __builtin_fmaf(r, gg - xs, xs);
        op[(size_t)(s * 16 + i) * 16384] = h;
      }
      FENCE();  // keep this stage's LDS reads inside the stage window
    }
    out[(size_t)16777216 + ob] = c;  // c_last
  }
}

extern "C" void kernel_launch(void* const* d_in, const int* in_sizes, int n_in,
                              void* d_out, int out_size, void* d_ws, size_t ws_size,
                              hipStream_t stream) {
  const float* x = (const float*)d_in[0];     // (1024,32,512) fp32
  const float* w = (const float*)d_in[1];     // (512,1536)    fp32
  const float* wc = (const float*)d_in[2];    // (1024,)       fp32
  const float* bias = (const float*)d_in[3];  // (1024,)       fp32
  const float* c0 = (const float*)d_in[4];    // (32,512)      fp32
  float* out = (float*)d_out;                 // h (L,B,d) | c_last (B,d)

  char* ws = (char*)d_ws;
  __bf16* wt = (__bf16*)ws;             // 1,572,864 B
  __bf16* u = (__bf16*)(ws + 1572864);  // 100,663,296 B

  cvt_w<<<dim3(8, 24), 256, 0, stream>>>(w, wt);
  dim3 gg(12, 256);
  gemm_kernel<<<gg, 256, 0, stream>>>(x, wt, u);
  scan_kernel<<<256, 128, 0, stream>>>(u, x, wc, bias, c0, out);
}